// Round 1
// baseline (213.462 us; speedup 1.0000x reference)
//
#include <hip/hip_runtime.h>
#include <stdint.h>

// CSSA: B=32, H=W=64, C=64, heads=4, hd=16, strip windows 64x8 -> 256 windows.
// Round 7: block=(window,head), 512 thr = 8 waves, wave = 64 queries (4 tiles).
//  - K staged fragment-blocked Kl[chunk][quad][row][4] -> kf ds_read_b64 is a
//    contiguous 512B lane-linear tile per chunk => bank-conflict-free.
//  - Keys PERMUTED at staging (sigma(c,m) = 32*blk + 8*u + 4*half + r) so the
//    two 16x16x16 QK C-frags of a 32-key block give each lane exactly keys
//    8*quad..8*quad+7 == the B-frag of ONE mfma_f32_16x16x32_bf16 PV step
//    (k = 8*(lane>>4)+i, consecutive-8 layout per m92/m97 b128-frag evidence).
//    PV MFMAs halve (128->64/wave); V A-frag = one aligned ds_read_b128 of 8
//    consecutive tokens (stride 260 dw == 4 mod 32 -> each 16-lane phase hits
//    all 32 banks exactly once: conflict-free).
//  - Epilogue: OOB conv taps redirect to zeroed pad col 512 (no weight
//    cndmask, no &511), Wl padded to stride 10 for b64-pair weight reads.
//  - Staging converts via cvt_pk (1 op / 2 elems).
// LDS: 16384 (Kl) + 16640 (Vt) + 640 + 64 = 33.7 KB -> 4 blocks/CU headroom.

#define VSTR 520    // Vt row: 512 tok + 8 pad (col 512 zeroed = OOB tap target)

typedef __attribute__((ext_vector_type(4))) short          short4v;
typedef __attribute__((ext_vector_type(4))) float          f32x4;
typedef __attribute__((ext_vector_type(4))) unsigned short us4;
typedef __bf16 bf2_t  __attribute__((ext_vector_type(2)));
typedef __bf16 bf16x8 __attribute__((ext_vector_type(8)));

__device__ __forceinline__ float bf2f(unsigned short u) {
    union { unsigned int i; float f; } x; x.i = ((unsigned int)u) << 16; return x.f;
}
__device__ __forceinline__ unsigned int pk2bf(float lo, float hi) {
#if __has_builtin(__builtin_amdgcn_cvt_pk_bf16_f32)
    union { bf2_t v; unsigned int u; } c;
    c.v = __builtin_amdgcn_cvt_pk_bf16_f32(lo, hi);     // 1 VALU op
    return c.u;
#else
    union { float f; unsigned int u; } a, b; a.f = lo; b.f = hi;
    return __builtin_amdgcn_perm(b.u + 0x8000u, a.u + 0x8000u, 0x07060302u);
#endif
}
__device__ __forceinline__ short4v pk4bf(float a, float b, float c, float d) {
    union { short4v s; unsigned int u[2]; } p;
    p.u[0] = pk2bf(a, b);
    p.u[1] = pk2bf(c, d);
    return p.s;
}

__global__ __launch_bounds__(512, 6)
void CSSA_69355131896243_kernel(const float* __restrict__ qkv,
                                const float* __restrict__ wconv,
                                const float* __restrict__ bconv,
                                float* __restrict__ out)
{
    __shared__ unsigned short Kl[32 * 256];   // 16384 B  frag-blocked K bf16
    __shared__ unsigned short Vt[16 * VSTR];  // 16640 B  V^T[d][token] bf16
    __shared__ float Wl[160];                 // 16 x (9 + 1 pad) conv weights
    __shared__ float Bl[16];

    const int tid  = threadIdx.x;
    const int wave = tid >> 6, lane = tid & 63, quad = lane >> 4, l15 = lane & 15;

    // bid -> (window, head): head-siblings of a window are 8 apart -> same XCD
    // under round-robin dispatch -> shared Q/K/V/out lines merge in L2.
    const int bid = blockIdx.x;
    const int win = (bid & 7) * 32 + (bid >> 5);
    const int h   = (bid >> 3) & 3;
    const int b   = win >> 3, wx = win & 7;

    const size_t ONE  = (size_t)32 * 4096 * 64;
    const size_t base = ((size_t)b * 4096 + (size_t)wx * 8) * 64;
    const float* gQ = qkv + base;
    const float* gK = qkv + ONE + base;
    const float* gV = qkv + 2 * ONE + base;
    const int hc = h * 16;

    // ---- stage this head's K (permuted, frag-blocked) + V^T as bf16 ----
    {
        const int c4 = tid & 3;          // 4-ch group within head == quad role
        const int t0 = tid >> 2;         // 128 tokens per round
        #pragma unroll
        for (int r = 0; r < 4; ++r) {
            const int t = r * 128 + t0;
            const size_t goff = (size_t)(t >> 3) * 4096 + (size_t)(t & 7) * 64 + hc + c4 * 4;
            f32x4 kd = *(const f32x4*)(gK + goff);
            f32x4 vd = *(const f32x4*)(gV + goff);
            union { us4 v; unsigned int u[2]; } kb;
            kb.u[0] = pk2bf(kd[0], kd[1]);
            kb.u[1] = pk2bf(kd[2], kd[3]);
            // key t = 32*blk + 8*u + 4*half + r  ->  chunk 2*blk+half, row 4*u+r
            const int cc = 2 * (t >> 5) + ((t >> 2) & 1);
            const int m  = ((t >> 3) & 3) * 4 + (t & 3);
            *(us4*)(&Kl[(cc * 4 + c4) * 64 + m * 4]) = kb.v;
            const unsigned int v01 = pk2bf(vd[0], vd[1]);
            const unsigned int v23 = pk2bf(vd[2], vd[3]);
            Vt[(c4 * 4 + 0) * VSTR + t] = (unsigned short)(v01 & 0xffffu);
            Vt[(c4 * 4 + 1) * VSTR + t] = (unsigned short)(v01 >> 16);
            Vt[(c4 * 4 + 2) * VSTR + t] = (unsigned short)(v23 & 0xffffu);
            Vt[(c4 * 4 + 3) * VSTR + t] = (unsigned short)(v23 >> 16);
        }
    }
    if (tid < 16)  Vt[tid * VSTR + 512] = 0;                       // OOB tap -> 0
    if (tid < 144) Wl[(tid / 9) * 10 + (tid % 9)] = wconv[h * 144 + tid];
    if (tid < 16)  Bl[tid] = bconv[hc + tid];

    // ---- Q prefetch + pack (independent of LDS -> overlaps barrier wait) ----
    const float SCL = 0.25f * 1.44269504088896341f;   // scale*log2(e) folded in
    const int q0 = wave * 64;
    short4v qf[4];   // B[k=d=quad*4+i][n=q=l15]
    #pragma unroll
    for (int t = 0; t < 4; ++t) {
        const int q = q0 + t * 16 + l15;
        f32x4 qv = *(const f32x4*)(gQ + (size_t)(q >> 3) * 4096 + (size_t)(q & 7) * 64 + hc + quad * 4);
        qf[t] = pk4bf(qv[0] * SCL, qv[1] * SCL, qv[2] * SCL, qv[3] * SCL);
    }
    __syncthreads();

    f32x4 acc[4];
    float lp[4];
    #pragma unroll
    for (int t = 0; t < 4; ++t) { acc[t] = (f32x4)0.0f; lp[t] = 0.0f; }

    // ---- main loop: 16 blocks x 32 keys ----
    const unsigned short* Kf = &Kl[quad * 64 + l15 * 4];     // + c*256 per chunk
    const unsigned short* Vf = &Vt[l15 * VSTR + quad * 8];   // + blk*32

    #pragma unroll 2
    for (int blk = 0; blk < 16; ++blk) {
        // K A-frags (chunks 2*blk, 2*blk+1): A[m=row=l15][k=d=quad*4+i]
        const short4v kfA = *(const short4v*)(Kf + blk * 512);
        const short4v kfB = *(const short4v*)(Kf + blk * 512 + 256);
        // V A-frag for K=32 PV: A[m=d=l15][k=key=8*quad+i], 8 consecutive tokens
        const bf16x8 vf = *(const bf16x8*)(Vf + blk * 32);
        #pragma unroll
        for (int t = 0; t < 4; ++t) {
            // sA rows = keys 32*blk + 8*quad + (0..3); sB rows = + (4..7)
            f32x4 sA = __builtin_amdgcn_mfma_f32_16x16x16bf16_1k(kfA, qf[t], (f32x4)0.0f, 0, 0, 0);
            f32x4 sB = __builtin_amdgcn_mfma_f32_16x16x16bf16_1k(kfB, qf[t], (f32x4)0.0f, 0, 0, 0);
            const float p0 = __builtin_amdgcn_exp2f(sA[0]);
            const float p1 = __builtin_amdgcn_exp2f(sA[1]);
            const float p2 = __builtin_amdgcn_exp2f(sA[2]);
            const float p3 = __builtin_amdgcn_exp2f(sA[3]);
            const float p4 = __builtin_amdgcn_exp2f(sB[0]);
            const float p5 = __builtin_amdgcn_exp2f(sB[1]);
            const float p6 = __builtin_amdgcn_exp2f(sB[2]);
            const float p7 = __builtin_amdgcn_exp2f(sB[3]);
            lp[t] += ((p0 + p1) + (p2 + p3)) + ((p4 + p5) + (p6 + p7));
            // P B-frag: elems 0..7 = keys 8*quad+0..7 at col q=l15 -> one K=32 PV
            union { bf16x8 v; unsigned int u[4]; } pb;
            pb.u[0] = pk2bf(p0, p1); pb.u[1] = pk2bf(p2, p3);
            pb.u[2] = pk2bf(p4, p5); pb.u[3] = pk2bf(p6, p7);
            acc[t] = __builtin_amdgcn_mfma_f32_16x16x32_bf16(vf, pb.v, acc[t], 0, 0, 0);
        }
    }

    // ---- denominators: cross-quad reduce ----
    float linv[4];
    #pragma unroll
    for (int t = 0; t < 4; ++t) {
        float v = lp[t];
        v += __shfl_xor(v, 16, 64);
        v += __shfl_xor(v, 32, 64);
        linv[t] = __builtin_amdgcn_rcpf(v);
    }

    // ---- epilogue: LePE from resident V^T, normalize, f32x4 stores ----
    const int xb = l15 & 7;   // x = q&7 is t-invariant (q0, t*16 are mult of 8)
    #pragma unroll
    for (int j = 0; j < 4; ++j) {
        const int d = quad * 4 + j;
        float w9[9];
        #pragma unroll
        for (int o = 0; o < 9; ++o) w9[o] = Wl[d * 10 + o];
        const float bs = Bl[d];
        const unsigned short* vrow = &Vt[d * VSTR];
        #pragma unroll
        for (int t = 0; t < 4; ++t) {
            const int q = q0 + t * 16 + l15;
            const int y = q >> 3;
            float lep = bs;
            #pragma unroll
            for (int dy = 0; dy < 3; ++dy) {
                const int yy  = y + dy - 1;
                const bool oky = ((unsigned)yy < 64u);
                const int yy8 = yy * 8;
                #pragma unroll
                for (int dx = 0; dx < 3; ++dx) {
                    const int xx = xb + dx - 1;
                    const bool ok = oky && ((unsigned)xx < 8u);
                    const int ta = ok ? (yy8 + xx) : 512;   // 512 -> reads 0.0
                    lep += w9[dy * 3 + dx] * bf2f(vrow[ta]);
                }
            }
            acc[t][j] = acc[t][j] * linv[t] + lep;
        }
    }
    float* gO = out + base;
    #pragma unroll
    for (int t = 0; t < 4; ++t) {
        const int q = q0 + t * 16 + l15;
        *(f32x4*)(gO + (size_t)(q >> 3) * 4096 + (size_t)(q & 7) * 64 + hc + quad * 4) = acc[t];
    }
}

extern "C" void kernel_launch(void* const* d_in, const int* in_sizes, int n_in,
                              void* d_out, int out_size, void* d_ws, size_t ws_size,
                              hipStream_t stream) {
    const float* qkv   = (const float*)d_in[0];
    const float* wconv = (const float*)d_in[1];
    const float* bconv = (const float*)d_in[2];
    float* outp = (float*)d_out;
    hipLaunchKernelGGL(CSSA_69355131896243_kernel, dim3(1024), dim3(512), 0, stream,
                       qkv, wconv, bconv, outp);
}